// Round 8
// baseline (156.697 us; speedup 1.0000x reference)
//
#include <hip/hip_runtime.h>

// out = x + softmax((x@Wq) @ (rs@Wk)^T) @ (rs@Wv)
// B=4 T=8 N=2048 C=D=128 M=2048. fp32 in/out, fp16 MFMA compute (f32 accum).
// R7: 512-thr blocks = 4 q-groups x 2 kv-groups. Each wave: 32 q-rows,
//     kv-half of each 64-kv tile -> DS traffic constant, per-wave work
//     halved, 4 waves/SIMD (16/CU). Flash-style kv-half merge at epilogue.

#define Bn 4
#define Tn 8
#define Nn 2048
#define Cn 128
#define Mn 2048
#define KVB 64
#define NT 32            // Mn/KVB
#define QROWS 128
#define NQT (Nn / QROWS) // 16

typedef __attribute__((ext_vector_type(4))) float f32x4;
typedef __attribute__((ext_vector_type(8))) _Float16 f16x8;
typedef __attribute__((address_space(3))) unsigned char lds_uc;
typedef const __attribute__((address_space(1))) unsigned char glb_uc;

__device__ __forceinline__ unsigned short f2h(float f) {
  _Float16 h = (_Float16)f;
  return __builtin_bit_cast(unsigned short, h);
}
__device__ __forceinline__ unsigned int pk2(float a, float b) {
  auto v = __builtin_amdgcn_cvt_pkrtz(a, b);
  return __builtin_bit_cast(unsigned int, v);
}
// 16B LDS read, 256B rows, swizzle (row&7)<<4
__device__ __forceinline__ f16x8 lds_read8(const unsigned char* base, int row,
                                           int colByte) {
  int byte = row * 256 + (colByte ^ ((row & 7) << 4));
  return *(const f16x8*)(base + byte);
}
__device__ __forceinline__ void gld16(const void* g, void* l) {
  __builtin_amdgcn_global_load_lds((glb_uc*)g, (lds_uc*)l, 16, 0, 0);
}

// ---------------------------------------------------------------------------
// Kernel A: per (b,kt): K tile [64 m][128 d] f16, 256B rows, swz (m&7)<<4;
// V^T tile super-row packed: srow=d>>1 (64 rows x 256B), within row:
// (d&1)*128 + m*2, swz ((d>>1)&7)<<4. Tiles contiguous 16KB each.
// grid: B*32 = 128 blocks, 256 threads.
// ---------------------------------------------------------------------------
__global__ __launch_bounds__(256) void proj_kv_kernel(
    const float* __restrict__ rs, const float* __restrict__ Wk,
    const float* __restrict__ Wv, unsigned short* __restrict__ k_ws,
    unsigned short* __restrict__ vt_ws) {
  __shared__ unsigned char smem[48 * 1024];
  unsigned char* rsh = smem;             // [64][128] f16 swz (16KB)
  unsigned char* wt = smem + 16 * 1024;  // [128][128] f16 swz, W^T (32KB)

  const int bid = blockIdx.x;
  const int b = bid >> 5;
  const int kt = bid & 31;
  const int m0 = kt << 6;
  const int tid = threadIdx.x;
  const int wv = tid >> 6, lane = tid & 63;

  {
    const float4* g = (const float4*)(rs + ((size_t)b * Mn + m0) * Cn);
#pragma unroll
    for (int i = 0; i < 8; ++i) {
      int f = tid + i * 256;
      int row = f >> 5, c4 = f & 31;
      float4 v = g[f];
      int byte = row * 256 + ((c4 * 8) ^ ((row & 7) << 4));
      *(ushort4*)(rsh + byte) =
          make_ushort4(f2h(v.x), f2h(v.y), f2h(v.z), f2h(v.w));
    }
  }

#define STAGE_WT(Wp)                                                          \
  {                                                                           \
    const float4* g = (const float4*)(Wp);                                    \
    _Pragma("unroll") for (int i = 0; i < 16; ++i) {                          \
      int f = tid + i * 256;                                                  \
      int cc = f >> 5, d0 = (f & 31) * 4;                                     \
      float4 v = g[f];                                                        \
      float vv[4] = {v.x, v.y, v.z, v.w};                                     \
      _Pragma("unroll") for (int j = 0; j < 4; ++j) {                         \
        int row = d0 + j;                                                     \
        int byte = row * 256 + ((cc * 2) ^ ((row & 7) << 4));                 \
        *(unsigned short*)(wt + byte) = f2h(vv[j]);                           \
      }                                                                       \
    }                                                                         \
  }

  STAGE_WT(Wk);
  __syncthreads();

  const int arow = wv * 16 + (lane & 15);
  f16x8 ah[4];
#pragma unroll
  for (int ks = 0; ks < 4; ++ks)
    ah[ks] = lds_read8(rsh, arow, (lane >> 4) * 16 + ks * 64);

  f32x4 acc[8];
#pragma unroll
  for (int df = 0; df < 8; ++df) acc[df] = (f32x4)(0.0f);
#pragma unroll
  for (int ks = 0; ks < 4; ++ks)
#pragma unroll
    for (int df = 0; df < 8; ++df) {
      f16x8 bf = lds_read8(wt, df * 16 + (lane & 15), (lane >> 4) * 16 + ks * 64);
      acc[df] = __builtin_amdgcn_mfma_f32_16x16x32_f16(ah[ks], bf, acc[df], 0, 0, 0);
    }
  {
    unsigned char* kb =
        (unsigned char*)k_ws + ((size_t)b * NT + kt) * 16384;
#pragma unroll
    for (int df = 0; df < 8; ++df)
#pragma unroll
      for (int r = 0; r < 4; ++r) {
        int row = wv * 16 + (lane >> 4) * 4 + r;   // tile-local m 0..63
        int dcol = df * 16 + (lane & 15);
        int byte = row * 256 + ((dcol * 2) ^ ((row & 7) << 4));
        *(unsigned short*)(kb + byte) = f2h(acc[df][r]);
      }
  }
  __syncthreads();

  STAGE_WT(Wv);
  __syncthreads();
#pragma unroll
  for (int df = 0; df < 8; ++df) acc[df] = (f32x4)(0.0f);
#pragma unroll
  for (int ks = 0; ks < 4; ++ks)
#pragma unroll
    for (int df = 0; df < 8; ++df) {
      f16x8 bf = lds_read8(wt, df * 16 + (lane & 15), (lane >> 4) * 16 + ks * 64);
      acc[df] = __builtin_amdgcn_mfma_f32_16x16x32_f16(ah[ks], bf, acc[df], 0, 0, 0);
    }
  {
    unsigned char* vb =
        (unsigned char*)vt_ws + ((size_t)b * NT + kt) * 16384;
#pragma unroll
    for (int df = 0; df < 8; ++df)
#pragma unroll
      for (int r = 0; r < 4; ++r) {
        int row = wv * 16 + (lane >> 4) * 4 + r;   // tile-local m
        int dcol = df * 16 + (lane & 15);          // d
        int byte = (dcol >> 1) * 256 +
                   ((((dcol & 1) << 7) + row * 2) ^ (((dcol >> 1) & 7) << 4));
        *(unsigned short*)(vb + byte) = f2h(acc[df][r]);
      }
  }
#undef STAGE_WT
}

// ---------------------------------------------------------------------------
// Kernel B: flash attention, 512 blocks x 512 thr (8 waves).
// wave = qg (wv&3: 32 q-rows) x kvg (wv>>2: kv-half of each tile).
// LDS 80KB: prologue wq^T/q @0 (32K); main K[2] @0/16K, V[2] @32K/48K,
// P @64K + wv*2K; epilogue ML @64K, O-partial f16 @0, bounce @32K.
// ---------------------------------------------------------------------------
__global__ __launch_bounds__(512, 4) void attn_kernel(
    const float* __restrict__ x, const float* __restrict__ Wq,
    const unsigned short* __restrict__ k_ws,
    const unsigned short* __restrict__ vt_ws, float* __restrict__ out) {
  __shared__ unsigned char smem[80 * 1024];

  const int bx = blockIdx.x;
  const int wb = ((bx & 7) << 6) | (bx >> 3);  // XCD swizzle (512 % 8 == 0)
  const int b = wb >> 7;
  const int t_ = (wb >> 4) & 7;
  const int n0 = (wb & 15) * QROWS;
  const int tid = threadIdx.x;
  const int wv = tid >> 6, lane = tid & 63;
  const int qg = wv & 3, kvg = wv >> 2;
  const int c = lane & 15, g = lane >> 4;

  const float* xg = x + (((size_t)b * Tn + t_) * Nn + n0) * Cn;  // 128x128
  unsigned char* pbw = smem + 64 * 1024 + wv * 2048;

  // ---- prologue: q = x@Wq (Wq pre-scaled by log2e), frags in regs ----
  const float LOG2E = 1.4426950408889634f;
  {
    const float4* gp = (const float4*)Wq;
#pragma unroll
    for (int ii = 0; ii < 8; ++ii) {
      int f = tid + ii * 512;
      int cc = f >> 5, d0 = (f & 31) * 4;
      float4 v = gp[f];
      float vv[4] = {v.x, v.y, v.z, v.w};
#pragma unroll
      for (int j = 0; j < 4; ++j) {
        int row = d0 + j;
        int byte = row * 256 + ((cc * 2) ^ ((row & 7) << 4));
        *(unsigned short*)(smem + byte) = f2h(vv[j] * LOG2E);
      }
    }
  }
  __syncthreads();

  f32x4 qacc[2][8];
#pragma unroll
  for (int rb = 0; rb < 2; ++rb)
#pragma unroll
    for (int df = 0; df < 8; ++df) qacc[rb][df] = (f32x4)(0.0f);
  {
    f16x8 xf[2][4];
#pragma unroll
    for (int rb = 0; rb < 2; ++rb) {
      const float* xrow = xg + (size_t)(qg * 32 + rb * 16 + c) * Cn;
#pragma unroll
      for (int ks = 0; ks < 4; ++ks) {
        int d0 = ks * 32 + g * 8;
        float4 a = *(const float4*)(xrow + d0);
        float4 b2 = *(const float4*)(xrow + d0 + 4);
        f16x8 h;
        h[0] = (_Float16)a.x; h[1] = (_Float16)a.y;
        h[2] = (_Float16)a.z; h[3] = (_Float16)a.w;
        h[4] = (_Float16)b2.x; h[5] = (_Float16)b2.y;
        h[6] = (_Float16)b2.z; h[7] = (_Float16)b2.w;
        xf[rb][ks] = h;
      }
    }
#pragma unroll
    for (int ks = 0; ks < 4; ++ks)
#pragma unroll
      for (int df = 0; df < 8; ++df) {
        f16x8 bf = lds_read8(smem, df * 16 + c, g * 16 + ks * 64);
        qacc[0][df] = __builtin_amdgcn_mfma_f32_16x16x32_f16(xf[0][ks], bf, qacc[0][df], 0, 0, 0);
        qacc[1][df] = __builtin_amdgcn_mfma_f32_16x16x32_f16(xf[1][ks], bf, qacc[1][df], 0, 0, 0);
      }
  }
  __syncthreads();  // all waves done reading Wq
  if (kvg == 0) {   // write q (f16) [128 q][128 dq] swz into @0
#pragma unroll
    for (int rb = 0; rb < 2; ++rb)
#pragma unroll
      for (int df = 0; df < 8; ++df)
#pragma unroll
        for (int r = 0; r < 4; ++r) {
          int row = qg * 32 + rb * 16 + g * 4 + r;
          int dq = df * 16 + c;
          int byte = row * 256 + ((dq * 2) ^ ((row & 7) << 4));
          *(unsigned short*)(smem + byte) = f2h(qacc[rb][df][r]);
        }
  }
  __syncthreads();
  f16x8 qf[2][4];
#pragma unroll
  for (int rb = 0; rb < 2; ++rb)
#pragma unroll
    for (int ks = 0; ks < 4; ++ks)
      qf[rb][ks] = lds_read8(smem, qg * 32 + rb * 16 + c, g * 16 + ks * 64);
  __syncthreads();  // before staging overwrites @0

  // ---- main flash loop ----
  f32x4 o[2][8];
#pragma unroll
  for (int rb = 0; rb < 2; ++rb)
#pragma unroll
    for (int df = 0; df < 8; ++df) o[rb][df] = (f32x4)(0.0f);
  float mrow[2] = {-INFINITY, -INFINITY};
  float lrow[2] = {0.f, 0.f};

  const unsigned char* khg = (const unsigned char*)k_ws + (size_t)b * NT * 16384;
  const unsigned char* vtg = (const unsigned char*)vt_ws + (size_t)b * NT * 16384;

  auto stage = [&](int t) {
    unsigned char* kd = smem + (t & 1) * 16384 + tid * 16;
    unsigned char* vd = smem + 32 * 1024 + (t & 1) * 16384 + tid * 16;
    const unsigned char* ks_ = khg + (size_t)t * 16384 + tid * 16;
    const unsigned char* vs = vtg + (size_t)t * 16384 + tid * 16;
    gld16(ks_, kd);
    gld16(ks_ + 8192, kd + 8192);
    gld16(vs, vd);
    gld16(vs + 8192, vd + 8192);
  };

  stage(0);
  __syncthreads();

#pragma unroll 1
  for (int t = 0; t < NT; ++t) {
    unsigned char* kb = smem + (t & 1) * 16384;
    unsigned char* vb = smem + 32 * 1024 + (t & 1) * 16384;
    if (t + 1 < NT) stage(t + 1);

    // QK^T: S^T[kv-half 32][q 32]
    f32x4 st[2][2];
#pragma unroll
    for (int rb = 0; rb < 2; ++rb)
#pragma unroll
      for (int kvb = 0; kvb < 2; ++kvb) st[rb][kvb] = (f32x4)(0.0f);
    __builtin_amdgcn_s_setprio(1);
#pragma unroll
    for (int ks = 0; ks < 4; ++ks)
#pragma unroll
      for (int kvb = 0; kvb < 2; ++kvb) {
        f16x8 kf = lds_read8(kb, kvg * 32 + kvb * 16 + c, g * 16 + ks * 64);
        st[0][kvb] = __builtin_amdgcn_mfma_f32_16x16x32_f16(kf, qf[0][ks], st[0][kvb], 0, 0, 0);
        st[1][kvb] = __builtin_amdgcn_mfma_f32_16x16x32_f16(kf, qf[1][ks], st[1][kvb], 0, 0, 0);
      }
    __builtin_amdgcn_s_setprio(0);

    // online softmax (log2 units), defer-max, pack P
#pragma unroll
    for (int rb = 0; rb < 2; ++rb) {
      float tm = fmaxf(fmaxf(fmaxf(st[rb][0][0], st[rb][0][1]),
                             fmaxf(st[rb][0][2], st[rb][0][3])),
                       fmaxf(fmaxf(st[rb][1][0], st[rb][1][1]),
                             fmaxf(st[rb][1][2], st[rb][1][3])));
      if (__any(tm > mrow[rb] + 8.f)) {  // rare path
        tm = fmaxf(tm, __shfl_xor(tm, 16));
        tm = fmaxf(tm, __shfl_xor(tm, 32));
        float newm = fmaxf(mrow[rb], tm);
        float scl = exp2f(mrow[rb] - newm);
#pragma unroll
        for (int df = 0; df < 8; ++df) o[rb][df] *= scl;
        lrow[rb] *= scl;
        mrow[rb] = newm;
      }
      float mn = mrow[rb];
      float ps = 0.f;
#pragma unroll
      for (int kvb = 0; kvb < 2; ++kvb) {
        float p0 = exp2f(st[rb][kvb][0] - mn);
        float p1 = exp2f(st[rb][kvb][1] - mn);
        float p2 = exp2f(st[rb][kvb][2] - mn);
        float p3 = exp2f(st[rb][kvb][3] - mn);
        ps += (p0 + p1) + (p2 + p3);
        int row = rb * 16 + c;
        int kv2 = kvb * 32 + g * 8;  // kv-local * 2 bytes
        int swz = (c & 3) << 4;
        *(unsigned int*)(pbw + row * 64 + (kv2 ^ swz)) = pk2(p0, p1);
        *(unsigned int*)(pbw + row * 64 + ((kv2 + 4) ^ swz)) = pk2(p2, p3);
      }
      lrow[rb] += ps;
    }

    // P fragments (in-wave write->read)
    f16x8 pa[2];
#pragma unroll
    for (int rb = 0; rb < 2; ++rb) {
      int row = rb * 16 + c;
      pa[rb] = *(const f16x8*)(pbw + row * 64 + ((g * 16) ^ ((c & 3) << 4)));
    }

    // PV: O^T[d][q] += V^T(kv-half) @ P, K=32 contraction
    __builtin_amdgcn_s_setprio(1);
#pragma unroll
    for (int df = 0; df < 8; ++df) {
      int srow = df * 8 + (c >> 1);
      int byte = srow * 256 +
                 ((((c & 1) << 7) | (kvg * 64 + g * 16)) ^ ((srow & 7) << 4));
      f16x8 vf = *(const f16x8*)(vb + byte);
      o[0][df] = __builtin_amdgcn_mfma_f32_16x16x32_f16(vf, pa[0], o[0][df], 0, 0, 0);
      o[1][df] = __builtin_amdgcn_mfma_f32_16x16x32_f16(vf, pa[1], o[1][df], 0, 0, 0);
    }
    __builtin_amdgcn_s_setprio(0);
    __syncthreads();
  }

  // ---- epilogue: merge kv-halves (flash merge), out = x + O/l ----
#pragma unroll
  for (int rb = 0; rb < 2; ++rb) {
    lrow[rb] += __shfl_xor(lrow[rb], 16);
    lrow[rb] += __shfl_xor(lrow[rb], 32);
  }
  float* ML = (float*)(smem + 64 * 1024);  // [8 wv][2 rb][16 c][2 {m,l}]
  if (g == 0) {
#pragma unroll
    for (int rb = 0; rb < 2; ++rb) {
      ML[((wv * 2 + rb) * 16 + c) * 2 + 0] = mrow[rb];
      ML[((wv * 2 + rb) * 16 + c) * 2 + 1] = lrow[rb];
    }
  }
  __syncthreads();
  const int pw = wv ^ 4;
  float coef[2];
#pragma unroll
  for (int rb = 0; rb < 2; ++rb) {
    float mp = ML[((pw * 2 + rb) * 16 + c) * 2 + 0];
    float lp = ML[((pw * 2 + rb) * 16 + c) * 2 + 1];
    float m12 = fmaxf(mrow[rb], mp);
    float s0 = exp2f(mrow[rb] - m12);
    float sp = exp2f(mp - m12);
    float ltot = lrow[rb] * s0 + lp * sp;
    coef[rb] = s0 / ltot;   // own-scale / total
  }
  __syncthreads();
  if (kvg == 1) {  // write own O*coef (f16) to @0 [128 q][128 d] swz
#pragma unroll
    for (int rb = 0; rb < 2; ++rb)
#pragma unroll
      for (int df = 0; df < 8; ++df)
#pragma unroll
        for (int h = 0; h < 2; ++h) {
          int row = qg * 32 + rb * 16 + c;
          int d0 = df * 16 + g * 4 + 2 * h;
          int byte = row * 256 + ((d0 * 2) ^ ((row & 7) << 4));
          *(unsigned int*)(smem + byte) =
              pk2(o[rb][df][2 * h] * coef[rb], o[rb][df][2 * h + 1] * coef[rb]);
        }
  }
  __syncthreads();
  if (kvg == 0) {  // merge + write bounce @32K
#pragma unroll
    for (int rb = 0; rb < 2; ++rb)
#pragma unroll
      for (int df = 0; df < 8; ++df)
#pragma unroll
        for (int h = 0; h < 2; ++h) {
          int row = qg * 32 + rb * 16 + c;
          int d0 = df * 16 + g * 4 + 2 * h;
          int sw = (d0 * 2) ^ ((row & 7) << 4);
          unsigned int v = *(const unsigned int*)(smem + row * 256 + sw);
          float plo = (float)__builtin_bit_cast(_Float16, (unsigned short)(v & 0xffffu));
          float phi = (float)__builtin_bit_cast(_Float16, (unsigned short)(v >> 16));
          float r0 = o[rb][df][2 * h] * coef[rb] + plo;
          float r1 = o[rb][df][2 * h + 1] * coef[rb] + phi;
          *(unsigned int*)(smem + 32 * 1024 + row * 256 + sw) = pk2(r0, r1);
        }
  }
  __syncthreads();
  {
    const float4* xg4 = (const float4*)xg;
    float4* og4 = (float4*)(out + (((size_t)b * Tn + t_) * Nn + n0) * Cn);
#pragma unroll
    for (int ii = 0; ii < 4; ++ii) {
      int f = tid + ii * 512;
      int row = f >> 4, c16 = f & 15;
      int byte = 32 * 1024 + row * 256 + ((c16 * 16) ^ ((row & 7) << 4));
      f16x8 v = *(const f16x8*)(smem + byte);
      float4 x0 = xg4[row * 32 + c16 * 2];
      float4 x1 = xg4[row * 32 + c16 * 2 + 1];
      og4[row * 32 + c16 * 2] =
          make_float4(x0.x + (float)v[0], x0.y + (float)v[1],
                      x0.z + (float)v[2], x0.w + (float)v[3]);
      og4[row * 32 + c16 * 2 + 1] =
          make_float4(x1.x + (float)v[4], x1.y + (float)v[5],
                      x1.z + (float)v[6], x1.w + (float)v[7]);
    }
  }
}

extern "C" void kernel_launch(void* const* d_in, const int* in_sizes, int n_in,
                              void* d_out, int out_size, void* d_ws,
                              size_t ws_size, hipStream_t stream) {
  const float* x = (const float*)d_in[0];
  const float* rs = (const float*)d_in[1];
  const float* Wq = (const float*)d_in[2];
  const float* Wk = (const float*)d_in[3];
  const float* Wv = (const float*)d_in[4];
  float* out = (float*)d_out;

  // ws: K f16 tiles [B][32][16KB] (2MB) | V^T tiles [B][32][16KB] (2MB)
  unsigned short* k_ws = (unsigned short*)d_ws;
  unsigned short* vt_ws = k_ws + (size_t)Bn * Mn * Cn;

  proj_kv_kernel<<<Bn * NT, 256, 0, stream>>>(rs, Wk, Wv, k_ws, vt_ws);
  attn_kernel<<<Bn * Tn * NQT, 512, 0, stream>>>(x, Wq, k_ws, vt_ws, out);
}